// Round 16
// baseline (22.299 us; speedup 1.0000x reference)
//
#include <hip/hip_runtime.h>

#define B_   1024
#define DIM_ 512
#define L_   512
#define NOUT 1536
#define G_   16    // interpolation grid points per batch
#define LDA  72    // BK=64 + 8 pad ushorts: 144 B rows, 16B-aligned, 2-way banks

typedef __attribute__((ext_vector_type(8))) short short8;
typedef __attribute__((ext_vector_type(4))) float f32x4;

// packed fp32x2 -> bf16x2 (RNE), one VALU op
__device__ __forceinline__ unsigned int cvtpk(float lo, float hi) {
  unsigned int r;
  asm("v_cvt_pk_bf16_f32 %0, %1, %2" : "=v"(r) : "v"(lo), "v"(hi));
  return r;
}

struct Chunk { float4 a0, a1, a2, a3, b0, b1, b2, b3; };  // 32 floats

// ---------------- Kernel A: fused cvt + MFMA GEMM + in_proj ----------------
// BK=64: 8 K-steps, 8 barriers (vs 16 at BK=32 — barrier stalls are ~half of
// GEMM time). 1-deep register prefetch (32 VGPR; R13's 2-deep x 32-float hit
// the 128-VGPR occupancy cliff). launch_bounds(256,4) pins <=128 VGPR.
// 64x64 tile, 4 waves x 32x32 quadrant, XCD swizzle, identical MFMA order.
__global__ __launch_bounds__(256, 4) void gemm_kernel(
    const float* __restrict__ x, const float* __restrict__ w,
    const float* __restrict__ ipw, const float* __restrict__ ipb,
    float* __restrict__ qp, float* __restrict__ kvp)
{
  __shared__ unsigned short aT[2][64 * LDA];   // 18 KB
  __shared__ unsigned short bT[2][64 * LDA];   // 18 KB

  const int tid  = threadIdx.x;
  const int lane = tid & 63;
  const int wv   = tid >> 6;
  const int bid  = blockIdx.x;
  const int xcd  = bid & 7, slot = bid >> 3;   // HW: xcd = dispatch_id % 8
  const int cb   = xcd * 3 + (slot >> 4);      // 3 col-tiles per XCD
  const int rb   = slot & 15;
  const int row0 = rb * 64;
  const int col0 = cb * 64;

  // staging: row sr (0..63), 16-float chunk sc (0,16,32,48)
  const int sr = tid >> 2;
  const int sc = (tid & 3) * 16;
  const float* xg = &x[(size_t)(row0 + sr) * DIM_ + sc];
  const float* wg = &w[(size_t)(col0 + sr) * DIM_ + sc];
  const int soff = sr * LDA + sc;

  const int wr = wv >> 1, wc = wv & 1;
  const int lm = lane & 15;
  const int kq = (lane >> 4) * 8;
  const int aoff0 = (wr * 32 + lm) * LDA + kq;
  const int boff0 = (wc * 32 + lm) * LDA + kq;

  f32x4 acc00 = {0,0,0,0}, acc01 = {0,0,0,0}, acc10 = {0,0,0,0}, acc11 = {0,0,0,0};

#define LOADC(dst, k0) do { \
    (dst).a0 = *(const float4*)(xg + (k0));      \
    (dst).a1 = *(const float4*)(xg + (k0) + 4);  \
    (dst).a2 = *(const float4*)(xg + (k0) + 8);  \
    (dst).a3 = *(const float4*)(xg + (k0) + 12); \
    (dst).b0 = *(const float4*)(wg + (k0));      \
    (dst).b1 = *(const float4*)(wg + (k0) + 4);  \
    (dst).b2 = *(const float4*)(wg + (k0) + 8);  \
    (dst).b3 = *(const float4*)(wg + (k0) + 12); } while (0)
#define STORE_LDS(src, buf) do { \
    uint4 av0_ = { cvtpk((src).a0.x,(src).a0.y), cvtpk((src).a0.z,(src).a0.w), \
                   cvtpk((src).a1.x,(src).a1.y), cvtpk((src).a1.z,(src).a1.w) }; \
    uint4 av1_ = { cvtpk((src).a2.x,(src).a2.y), cvtpk((src).a2.z,(src).a2.w), \
                   cvtpk((src).a3.x,(src).a3.y), cvtpk((src).a3.z,(src).a3.w) }; \
    uint4 bv0_ = { cvtpk((src).b0.x,(src).b0.y), cvtpk((src).b0.z,(src).b0.w), \
                   cvtpk((src).b1.x,(src).b1.y), cvtpk((src).b1.z,(src).b1.w) }; \
    uint4 bv1_ = { cvtpk((src).b2.x,(src).b2.y), cvtpk((src).b2.z,(src).b2.w), \
                   cvtpk((src).b3.x,(src).b3.y), cvtpk((src).b3.z,(src).b3.w) }; \
    *(uint4*)&aT[buf][soff]     = av0_; \
    *(uint4*)&aT[buf][soff + 8] = av1_; \
    *(uint4*)&bT[buf][soff]     = bv0_; \
    *(uint4*)&bT[buf][soff + 8] = bv1_; } while (0)

  Chunk c1;
  LOADC(c1, 0);
  STORE_LDS(c1, 0);
  LOADC(c1, 64);        // chunk 1 in flight across barrier + step-0 compute
  __syncthreads();

  int p = 0;
#pragma unroll 2
  for (int kc = 0; kc < 8; ++kc) {
#pragma unroll
    for (int kk = 0; kk < 2; ++kk) {
      const int ko = kk * 32;
      short8 a0 = *(const short8*)&aT[p][aoff0 + ko];
      short8 a1 = *(const short8*)&aT[p][aoff0 + 16 * LDA + ko];
      short8 b0 = *(const short8*)&bT[p][boff0 + ko];
      short8 b1 = *(const short8*)&bT[p][boff0 + 16 * LDA + ko];
      acc00 = __builtin_amdgcn_mfma_f32_16x16x32_bf16(a0, b0, acc00, 0, 0, 0);
      acc01 = __builtin_amdgcn_mfma_f32_16x16x32_bf16(a0, b1, acc01, 0, 0, 0);
      acc10 = __builtin_amdgcn_mfma_f32_16x16x32_bf16(a1, b0, acc10, 0, 0, 0);
      acc11 = __builtin_amdgcn_mfma_f32_16x16x32_bf16(a1, b1, acc11, 0, 0, 0);
    }
    if (kc < 7) {
      STORE_LDS(c1, p ^ 1);                    // c1 arrived a full step ago
      if (kc < 6) LOADC(c1, (kc + 2) * 64);    // refill; used next iteration
      __syncthreads();
      p ^= 1;
    }
  }
#undef LOADC
#undef STORE_LDS

  const float pw0 = ipw[0], pw1 = ipw[1], pw2 = ipw[2];
  const float pb0 = ipb[0], pb1 = ipb[1], pb2 = ipb[2];
  f32x4 accs[2][2] = {{acc00, acc01}, {acc10, acc11}};
#pragma unroll
  for (int cj = 0; cj < 2; ++cj) {
    const int o = col0 + wc * 32 + cj * 16 + lm;
    const int l = o / 3;
    const int c = o - 3 * l;
    const float pw = (c == 0) ? pw0 : ((c == 1) ? pw1 : pw2);
    const float pb = (c == 0) ? pb0 : ((c == 1) ? pb1 : pb2);
#pragma unroll
    for (int ri = 0; ri < 2; ++ri) {
#pragma unroll
      for (int r = 0; r < 4; ++r) {
        const int row = row0 + wr * 32 + ri * 16 + (lane >> 4) * 4 + r;
        const float v = fmaf(accs[ri][cj][r], pw, pb);
        if (c == 0) qp[(size_t)row * L_ + l] = v;
        else        kvp[(size_t)row * 2 * L_ + 2 * l + (c - 1)] = v;
      }
    }
  }
}

// ---------------- Kernel B: rank-1 attention via per-batch interpolation ---
// Frozen R15 winner: G_=16, one block per batch, padded segment layout,
// no runtime-indexed thread arrays.
__global__ __launch_bounds__(256) void attn_kernel(
    const float* __restrict__ qp, const float* __restrict__ kvp,
    const float* __restrict__ x, const float* __restrict__ ow,
    const float* __restrict__ ob, float* __restrict__ out)
{
  __shared__ float2 kvs[16 * 34];  // 16 segments x 32 pairs (+2 pad)
  __shared__ float2 part2[256];
  __shared__ float  fgrid[G_];
  __shared__ float  red[8];
  const int b = blockIdx.x, tid = threadIdx.x;
  const float2* __restrict__ kvg = (const float2*)&kvp[(size_t)b * 2 * L_];

  float q0 = qp[(size_t)b * L_ + tid];
  float q1 = qp[(size_t)b * L_ + 256 + tid];
  const float xres0 = x[(size_t)b * L_ + tid];
  const float xres1 = x[(size_t)b * L_ + 256 + tid];
  const float w0 = ow[0], b0 = ob[0];
  float2 t0 = kvg[tid], t1 = kvg[tid + 256];
  kvs[(tid >> 5) * 34 + (tid & 31)] = t0;
  const int j1 = tid + 256;
  kvs[(j1 >> 5) * 34 + (j1 & 31)] = t1;

  float qmn = fminf(q0, q1), qmx = fmaxf(q0, q1);
#pragma unroll
  for (int off = 32; off; off >>= 1) {
    qmn = fminf(qmn, __shfl_xor(qmn, off));
    qmx = fmaxf(qmx, __shfl_xor(qmx, off));
  }
  if ((tid & 63) == 0) { red[tid >> 6] = qmn; red[4 + (tid >> 6)] = qmx; }
  __syncthreads();
  qmn = fminf(fminf(red[0], red[1]), fminf(red[2], red[3]));
  qmx = fmaxf(fmaxf(red[4], red[5]), fmaxf(red[6], red[7]));

  const float L2E = 1.44269504f;
  const float range = qmx - qmn;
  const float hstep = range * (1.f / (G_ - 1));
  const int g   = tid & (G_ - 1);      // grid point 0..15
  const int seg = tid >> 4;            // j-segment 0..15 (32 terms each)
  const float gq = (qmn + hstep * (float)g) * L2E;
  float num = 0.f, den = 0.f;
  const float4* kv4 = (const float4*)&kvs[seg * 34];
#pragma unroll 4
  for (int j = 0; j < 16; ++j) {
    float4 pr = kv4[j];                // k,v,k,v (broadcast within 16-lane group)
    float e0 = __builtin_amdgcn_exp2f(gq * pr.x);
    den += e0; num = fmaf(e0, pr.y, num);
    float e1 = __builtin_amdgcn_exp2f(gq * pr.z);
    den += e1; num = fmaf(e1, pr.w, num);
  }
  part2[tid] = make_float2(num, den);
  __syncthreads();
  if (tid < G_) {
    float nsum = 0.f, dsum = 0.f;
#pragma unroll
    for (int s = 0; s < 16; ++s) {
      float2 pp = part2[tid + 16 * s];
      nsum += pp.x; dsum += pp.y;
    }
    fgrid[tid] = nsum / dsum;
  }
  __syncthreads();

  const float inv_h = (range > 1e-20f) ? (float)(G_ - 1) / range : 0.f;
#pragma unroll
  for (int ii = 0; ii < 2; ++ii) {
    const float q = ii ? q1 : q0;
    float u = (q - qmn) * inv_h;
    u = fminf(fmaxf(u, 0.f), (float)(G_ - 1));
    int gi = (int)u;
    gi = min(gi, G_ - 2);
    const float t = u - (float)gi;
    const float p0 = fgrid[max(gi - 1, 0)];
    const float p1 = fgrid[gi];
    const float p2 = fgrid[gi + 1];
    const float p3 = fgrid[min(gi + 2, G_ - 1)];
    // Catmull-Rom
    const float f = 0.5f * (2.f * p1 + t * ((p2 - p0)
                  + t * ((2.f * p0 - 5.f * p1 + 4.f * p2 - p3)
                  + t * (3.f * (p1 - p2) + p3 - p0))));
    const int i = ii * 256 + tid;
    out[(size_t)b * L_ + i] = fmaf(f, w0, b0) + (ii ? xres1 : xres0);
  }
}

extern "C" void kernel_launch(void* const* d_in, const int* in_sizes, int n_in,
                              void* d_out, int out_size, void* d_ws, size_t ws_size,
                              hipStream_t stream) {
  const float* x     = (const float*)d_in[0];
  const float* qkv_w = (const float*)d_in[1];
  const float* ipw   = (const float*)d_in[2];
  const float* ipb   = (const float*)d_in[3];
  const float* ow    = (const float*)d_in[4];
  const float* ob    = (const float*)d_in[5];
  float* out = (float*)d_out;

  char* ws = (char*)d_ws;
  float* qp  = (float*)(ws);            // 2.0 MB
  float* kvp = (float*)(ws + 2097152);  // 4.0 MB

  gemm_kernel<<<dim3(384), dim3(256), 0, stream>>>(x, qkv_w, ipw, ipb, qp, kvp);

  attn_kernel<<<dim3(B_), dim3(256), 0, stream>>>(qp, kvp, x, ow, ob, out);
}

// Round 17
// 20.880 us; speedup vs baseline: 1.0680x; 1.0680x over previous
//
#include <hip/hip_runtime.h>

#define B_   1024
#define DIM_ 512
#define L_   512
#define NOUT 1536
#define G_   16    // interpolation grid points per batch
#define LDA  40    // LDS row stride in ushorts (80 B): 2-way-max bank aliasing

typedef __attribute__((ext_vector_type(8))) short short8;
typedef __attribute__((ext_vector_type(4))) float f32x4;

// packed fp32x2 -> bf16x2 (RNE), one VALU op
__device__ __forceinline__ unsigned int cvtpk(float lo, float hi) {
  unsigned int r;
  asm("v_cvt_pk_bf16_f32 %0, %1, %2" : "=v"(r) : "v"(lo), "v"(hi));
  return r;
}

struct Chunk { float4 al, ah, bl, bh; };

// ---------------- Kernel A: fused cvt + MFMA GEMM + in_proj ----------------
// 64x48 tile/block, 512 blocks = EXACTLY 2 blocks/CU (384-block 64x64 left
// half the CUs 25% idle: makespan 2.0 vs work 1.5). BK=32, 2-deep register
// prefetch (R10 win), cvtpk staging, XCD swizzle (4 col-tiles/XCD).
// 4 waves x (16 rows x 48 cols): 3 MFMA + 4 ds_read_b128 per K-step.
__global__ __launch_bounds__(256) void gemm_kernel(
    const float* __restrict__ x, const float* __restrict__ w,
    const float* __restrict__ ipw, const float* __restrict__ ipb,
    float* __restrict__ qp, float* __restrict__ kvp)
{
  __shared__ unsigned short aT[2][64 * LDA];   // 10 KB
  __shared__ unsigned short bT[2][48 * LDA];   // 7.5 KB

  const int tid  = threadIdx.x;
  const int lane = tid & 63;
  const int wv   = tid >> 6;
  const int bid  = blockIdx.x;
  const int xcd  = bid & 7, slot = bid >> 3;   // HW: xcd = dispatch_id % 8
  const int cb   = xcd * 4 + (slot >> 4);      // 4 col-tiles per XCD
  const int rb   = slot & 15;
  const int row0 = rb * 64;
  const int col0 = cb * 48;

  // staging: A all 256 thr (64 rows x 8 floats); B waves 0-2 (48 rows x 8)
  const int sra = tid >> 2, sca = (tid & 3) * 8;
  const int srb = tid >> 2;                    // valid for tid < 192
  const float* xg = &x[(size_t)(row0 + sra) * DIM_ + sca];
  const float* wg = &w[(size_t)(col0 + (tid < 192 ? srb : 0)) * DIM_ + sca];
  const int soffA = sra * LDA + sca;
  const int soffB = srb * LDA + sca;

  // fragment reads: wave wv owns rows [wv*16, wv*16+16), cols 0..47
  const int lm = lane & 15;
  const int kq = (lane >> 4) * 8;
  const int aoff = (wv * 16 + lm) * LDA + kq;
  const int boff = lm * LDA + kq;

  f32x4 acc0 = {0,0,0,0}, acc1 = {0,0,0,0}, acc2 = {0,0,0,0};

#define LOADC(dst, k0) do { \
    (dst).al = *(const float4*)(xg + (k0));     \
    (dst).ah = *(const float4*)(xg + (k0) + 4); \
    if (tid < 192) { \
      (dst).bl = *(const float4*)(wg + (k0));     \
      (dst).bh = *(const float4*)(wg + (k0) + 4); } } while (0)
#define STORE_LDS(src, buf) do { \
    uint4 av_ = { cvtpk((src).al.x,(src).al.y), cvtpk((src).al.z,(src).al.w), \
                  cvtpk((src).ah.x,(src).ah.y), cvtpk((src).ah.z,(src).ah.w) }; \
    *(uint4*)&aT[buf][soffA] = av_; \
    if (tid < 192) { \
      uint4 bv_ = { cvtpk((src).bl.x,(src).bl.y), cvtpk((src).bl.z,(src).bl.w), \
                    cvtpk((src).bh.x,(src).bh.y), cvtpk((src).bh.z,(src).bh.w) }; \
      *(uint4*)&bT[buf][soffB] = bv_; } } while (0)

  Chunk c0, c1, c2;
  LOADC(c0, 0);
  STORE_LDS(c0, 0);
  LOADC(c1, 32);          // in flight across the barrier + chunk-0 compute
  __syncthreads();

  int p = 0;
#pragma unroll 2
  for (int kc = 0; kc < 16; ++kc) {
    if (kc + 2 < 16) LOADC(c2, (kc + 2) * 32);   // issue 2 steps ahead
    short8 a0 = *(const short8*)&aT[p][aoff];
    short8 b0 = *(const short8*)&bT[p][boff];
    short8 b1 = *(const short8*)&bT[p][boff + 16 * LDA];
    short8 b2 = *(const short8*)&bT[p][boff + 32 * LDA];
    acc0 = __builtin_amdgcn_mfma_f32_16x16x32_bf16(a0, b0, acc0, 0, 0, 0);
    acc1 = __builtin_amdgcn_mfma_f32_16x16x32_bf16(a0, b1, acc1, 0, 0, 0);
    acc2 = __builtin_amdgcn_mfma_f32_16x16x32_bf16(a0, b2, acc2, 0, 0, 0);
    if (kc < 15) {
      STORE_LDS(c1, p ^ 1);   // c1 arrived long ago; vmcnt wait ~free
      __syncthreads();
      p ^= 1;
      c1 = c2;
    }
  }
#undef LOADC
#undef STORE_LDS

  const float pw0 = ipw[0], pw1 = ipw[1], pw2 = ipw[2];
  const float pb0 = ipb[0], pb1 = ipb[1], pb2 = ipb[2];
  f32x4 accs[3] = {acc0, acc1, acc2};
#pragma unroll
  for (int cj = 0; cj < 3; ++cj) {
    const int o = col0 + cj * 16 + lm;
    const int l = o / 3;
    const int c = o - 3 * l;
    const float pw = (c == 0) ? pw0 : ((c == 1) ? pw1 : pw2);
    const float pb = (c == 0) ? pb0 : ((c == 1) ? pb1 : pb2);
#pragma unroll
    for (int r = 0; r < 4; ++r) {
      const int row = row0 + wv * 16 + (lane >> 4) * 4 + r;
      const float v = fmaf(accs[cj][r], pw, pb);
      if (c == 0) qp[(size_t)row * L_ + l] = v;
      else        kvp[(size_t)row * 2 * L_ + 2 * l + (c - 1)] = v;
    }
  }
}

// ---------------- Kernel B: rank-1 attention via per-batch interpolation ---
// Frozen R15 winner: G_=16, one block per batch, padded segment layout,
// no runtime-indexed thread arrays.
__global__ __launch_bounds__(256) void attn_kernel(
    const float* __restrict__ qp, const float* __restrict__ kvp,
    const float* __restrict__ x, const float* __restrict__ ow,
    const float* __restrict__ ob, float* __restrict__ out)
{
  __shared__ float2 kvs[16 * 34];  // 16 segments x 32 pairs (+2 pad)
  __shared__ float2 part2[256];
  __shared__ float  fgrid[G_];
  __shared__ float  red[8];
  const int b = blockIdx.x, tid = threadIdx.x;
  const float2* __restrict__ kvg = (const float2*)&kvp[(size_t)b * 2 * L_];

  float q0 = qp[(size_t)b * L_ + tid];
  float q1 = qp[(size_t)b * L_ + 256 + tid];
  const float xres0 = x[(size_t)b * L_ + tid];
  const float xres1 = x[(size_t)b * L_ + 256 + tid];
  const float w0 = ow[0], b0 = ob[0];
  float2 t0 = kvg[tid], t1 = kvg[tid + 256];
  kvs[(tid >> 5) * 34 + (tid & 31)] = t0;
  const int j1 = tid + 256;
  kvs[(j1 >> 5) * 34 + (j1 & 31)] = t1;

  float qmn = fminf(q0, q1), qmx = fmaxf(q0, q1);
#pragma unroll
  for (int off = 32; off; off >>= 1) {
    qmn = fminf(qmn, __shfl_xor(qmn, off));
    qmx = fmaxf(qmx, __shfl_xor(qmx, off));
  }
  if ((tid & 63) == 0) { red[tid >> 6] = qmn; red[4 + (tid >> 6)] = qmx; }
  __syncthreads();
  qmn = fminf(fminf(red[0], red[1]), fminf(red[2], red[3]));
  qmx = fmaxf(fmaxf(red[4], red[5]), fmaxf(red[6], red[7]));

  const float L2E = 1.44269504f;
  const float range = qmx - qmn;
  const float hstep = range * (1.f / (G_ - 1));
  const int g   = tid & (G_ - 1);      // grid point 0..15
  const int seg = tid >> 4;            // j-segment 0..15 (32 terms each)
  const float gq = (qmn + hstep * (float)g) * L2E;
  float num = 0.f, den = 0.f;
  const float4* kv4 = (const float4*)&kvs[seg * 34];
#pragma unroll 4
  for (int j = 0; j < 16; ++j) {
    float4 pr = kv4[j];                // k,v,k,v (broadcast within 16-lane group)
    float e0 = __builtin_amdgcn_exp2f(gq * pr.x);
    den += e0; num = fmaf(e0, pr.y, num);
    float e1 = __builtin_amdgcn_exp2f(gq * pr.z);
    den += e1; num = fmaf(e1, pr.w, num);
  }
  part2[tid] = make_float2(num, den);
  __syncthreads();
  if (tid < G_) {
    float nsum = 0.f, dsum = 0.f;
#pragma unroll
    for (int s = 0; s < 16; ++s) {
      float2 pp = part2[tid + 16 * s];
      nsum += pp.x; dsum += pp.y;
    }
    fgrid[tid] = nsum / dsum;
  }
  __syncthreads();

  const float inv_h = (range > 1e-20f) ? (float)(G_ - 1) / range : 0.f;
#pragma unroll
  for (int ii = 0; ii < 2; ++ii) {
    const float q = ii ? q1 : q0;
    float u = (q - qmn) * inv_h;
    u = fminf(fmaxf(u, 0.f), (float)(G_ - 1));
    int gi = (int)u;
    gi = min(gi, G_ - 2);
    const float t = u - (float)gi;
    const float p0 = fgrid[max(gi - 1, 0)];
    const float p1 = fgrid[gi];
    const float p2 = fgrid[gi + 1];
    const float p3 = fgrid[min(gi + 2, G_ - 1)];
    // Catmull-Rom
    const float f = 0.5f * (2.f * p1 + t * ((p2 - p0)
                  + t * ((2.f * p0 - 5.f * p1 + 4.f * p2 - p3)
                  + t * (3.f * (p1 - p2) + p3 - p0))));
    const int i = ii * 256 + tid;
    out[(size_t)b * L_ + i] = fmaf(f, w0, b0) + (ii ? xres1 : xres0);
  }
}

extern "C" void kernel_launch(void* const* d_in, const int* in_sizes, int n_in,
                              void* d_out, int out_size, void* d_ws, size_t ws_size,
                              hipStream_t stream) {
  const float* x     = (const float*)d_in[0];
  const float* qkv_w = (const float*)d_in[1];
  const float* ipw   = (const float*)d_in[2];
  const float* ipb   = (const float*)d_in[3];
  const float* ow    = (const float*)d_in[4];
  const float* ob    = (const float*)d_in[5];
  float* out = (float*)d_out;

  char* ws = (char*)d_ws;
  float* qp  = (float*)(ws);            // 2.0 MB
  float* kvp = (float*)(ws + 2097152);  // 4.0 MB

  gemm_kernel<<<dim3(512), dim3(256), 0, stream>>>(x, qkv_w, ipw, ipb, qp, kvp);

  attn_kernel<<<dim3(B_), dim3(256), 0, stream>>>(qp, kvp, x, ow, ob, out);
}

// Round 18
// 20.222 us; speedup vs baseline: 1.1027x; 1.0326x over previous
//
#include <hip/hip_runtime.h>

#define B_   1024
#define DIM_ 512
#define L_   512
#define NOUT 1536
#define G_   16    // interpolation grid points per batch
#define LDA  40    // LDS row stride in ushorts (80 B): 2-way-max bank aliasing

typedef __attribute__((ext_vector_type(8))) short short8;
typedef __attribute__((ext_vector_type(4))) float f32x4;

// packed fp32x2 -> bf16x2 (RNE), one VALU op
__device__ __forceinline__ unsigned int cvtpk(float lo, float hi) {
  unsigned int r;
  asm("v_cvt_pk_bf16_f32 %0, %1, %2" : "=v"(r) : "v"(lo), "v"(hi));
  return r;
}

struct Chunk { float4 al, ah, bl, bh; };

// ---------------- Kernel A: fused cvt + MFMA GEMM, raw o-major C -----------
// R15 main loop (64x64 tile, BK=32, 2-deep prefetch, cvtpk staging, XCD
// swizzle). NEW epilogue: store RAW C[row][o] contiguously — no o/3 division,
// no 3-way select, no plane interleave; 16-lane groups write consecutive
// 64B segments (fully coalesced). De-interleave + in_proj move to attn.
__global__ __launch_bounds__(256) void gemm_kernel(
    const float* __restrict__ x, const float* __restrict__ w,
    float* __restrict__ co)
{
  __shared__ unsigned short aT[2][64 * LDA];   // 10 KB
  __shared__ unsigned short bT[2][64 * LDA];   // 10 KB

  const int tid  = threadIdx.x;
  const int lane = tid & 63;
  const int wv   = tid >> 6;
  const int bid  = blockIdx.x;
  const int xcd  = bid & 7, slot = bid >> 3;   // HW: xcd = dispatch_id % 8
  const int cb   = xcd * 3 + (slot >> 4);      // 3 col-tiles per XCD
  const int rb   = slot & 15;
  const int row0 = rb * 64;
  const int col0 = cb * 64;

  const int sr = tid >> 2;
  const int sc = (tid & 3) * 8;
  const float* xg = &x[(size_t)(row0 + sr) * DIM_ + sc];
  const float* wg = &w[(size_t)(col0 + sr) * DIM_ + sc];
  const int soff = sr * LDA + sc;

  const int wr = wv >> 1, wc = wv & 1;
  const int lm = lane & 15;
  const int kq = (lane >> 4) * 8;
  const int aoff0 = (wr * 32 + lm) * LDA + kq;
  const int boff0 = (wc * 32 + lm) * LDA + kq;

  f32x4 acc00 = {0,0,0,0}, acc01 = {0,0,0,0}, acc10 = {0,0,0,0}, acc11 = {0,0,0,0};

#define LOADC(dst, k0) do { \
    (dst).al = *(const float4*)(xg + (k0));     \
    (dst).ah = *(const float4*)(xg + (k0) + 4); \
    (dst).bl = *(const float4*)(wg + (k0));     \
    (dst).bh = *(const float4*)(wg + (k0) + 4); } while (0)
#define STORE_LDS(src, buf) do { \
    uint4 av_ = { cvtpk((src).al.x,(src).al.y), cvtpk((src).al.z,(src).al.w), \
                  cvtpk((src).ah.x,(src).ah.y), cvtpk((src).ah.z,(src).ah.w) }; \
    uint4 bv_ = { cvtpk((src).bl.x,(src).bl.y), cvtpk((src).bl.z,(src).bl.w), \
                  cvtpk((src).bh.x,(src).bh.y), cvtpk((src).bh.z,(src).bh.w) }; \
    *(uint4*)&aT[buf][soff] = av_; \
    *(uint4*)&bT[buf][soff] = bv_; } while (0)

  Chunk c0, c1, c2;
  LOADC(c0, 0);
  STORE_LDS(c0, 0);
  LOADC(c1, 32);          // in flight across the barrier + chunk-0 compute
  __syncthreads();

  int p = 0;
#pragma unroll 2
  for (int kc = 0; kc < 16; ++kc) {
    if (kc + 2 < 16) LOADC(c2, (kc + 2) * 32);   // issue 2 steps ahead
    short8 a0 = *(const short8*)&aT[p][aoff0];
    short8 a1 = *(const short8*)&aT[p][aoff0 + 16 * LDA];
    short8 b0 = *(const short8*)&bT[p][boff0];
    short8 b1 = *(const short8*)&bT[p][boff0 + 16 * LDA];
    acc00 = __builtin_amdgcn_mfma_f32_16x16x32_bf16(a0, b0, acc00, 0, 0, 0);
    acc01 = __builtin_amdgcn_mfma_f32_16x16x32_bf16(a0, b1, acc01, 0, 0, 0);
    acc10 = __builtin_amdgcn_mfma_f32_16x16x32_bf16(a1, b0, acc10, 0, 0, 0);
    acc11 = __builtin_amdgcn_mfma_f32_16x16x32_bf16(a1, b1, acc11, 0, 0, 0);
    if (kc < 15) {
      STORE_LDS(c1, p ^ 1);   // c1 arrived long ago; vmcnt wait ~free
      __syncthreads();
      p ^= 1;
      c1 = c2;
    }
  }
#undef LOADC
#undef STORE_LDS

  // raw o-major store: contiguous 64B segments per 16-lane group
  f32x4 accs[2][2] = {{acc00, acc01}, {acc10, acc11}};
#pragma unroll
  for (int cj = 0; cj < 2; ++cj) {
    const int o = col0 + wc * 32 + cj * 16 + lm;
#pragma unroll
    for (int ri = 0; ri < 2; ++ri) {
#pragma unroll
      for (int r = 0; r < 4; ++r) {
        const int row = row0 + wr * 32 + ri * 16 + (lane >> 4) * 4 + r;
        co[(size_t)row * NOUT + o] = accs[ri][cj][r];
      }
    }
  }
}

// ---------------- Kernel B: rank-1 attention via per-batch interpolation ---
// Stages the raw 6KB C row coalesced (float4), then de-interleaves q/k/v via
// stride-3 LDS reads (gcd(3,32)=1 -> exactly 2-way bank alias = free) and
// applies in_proj affine (same fp32 fma order as before -> bit-identical).
// G_=16 grid + Catmull-Rom as in R15.
__global__ __launch_bounds__(256) void attn_kernel(
    const float* __restrict__ co, const float* __restrict__ x,
    const float* __restrict__ ipw, const float* __restrict__ ipb,
    const float* __restrict__ ow, const float* __restrict__ ob,
    float* __restrict__ out)
{
  __shared__ float  craw[NOUT];    // 6 KB raw C row
  __shared__ float2 kvs[16 * 34];  // 16 segments x 32 pairs (+2 pad)
  __shared__ float2 part2[256];
  __shared__ float  fgrid[G_];
  __shared__ float  red[8];
  const int b = blockIdx.x, tid = threadIdx.x;

  // coalesced staging of the raw row
  const float4* C4 = (const float4*)&co[(size_t)b * NOUT];
  float4* l4 = (float4*)craw;
  l4[tid] = C4[tid];
  if (tid < 128) l4[256 + tid] = C4[256 + tid];
  // hoisted residual loads
  const float xres0 = x[(size_t)b * L_ + tid];
  const float xres1 = x[(size_t)b * L_ + 256 + tid];
  const float pw0 = ipw[0], pw1 = ipw[1], pw2 = ipw[2];
  const float pb0 = ipb[0], pb1 = ipb[1], pb2 = ipb[2];
  const float w0 = ow[0], b0 = ob[0];
  __syncthreads();

  // de-interleave + in_proj (stride-3 LDS reads: 2-way alias, free)
  const float q0 = fmaf(craw[3 * tid], pw0, pb0);
  const float q1 = fmaf(craw[3 * (tid + 256)], pw0, pb0);
  {
    const float k0r = craw[3 * tid + 1],         v0r = craw[3 * tid + 2];
    const float k1r = craw[3 * (tid + 256) + 1], v1r = craw[3 * (tid + 256) + 2];
    kvs[(tid >> 5) * 34 + (tid & 31)] =
        make_float2(fmaf(k0r, pw1, pb1), fmaf(v0r, pw2, pb2));
    const int j1 = tid + 256;
    kvs[(j1 >> 5) * 34 + (j1 & 31)] =
        make_float2(fmaf(k1r, pw1, pb1), fmaf(v1r, pw2, pb2));
  }

  float qmn = fminf(q0, q1), qmx = fmaxf(q0, q1);
#pragma unroll
  for (int off = 32; off; off >>= 1) {
    qmn = fminf(qmn, __shfl_xor(qmn, off));
    qmx = fmaxf(qmx, __shfl_xor(qmx, off));
  }
  if ((tid & 63) == 0) { red[tid >> 6] = qmn; red[4 + (tid >> 6)] = qmx; }
  __syncthreads();
  qmn = fminf(fminf(red[0], red[1]), fminf(red[2], red[3]));
  qmx = fmaxf(fmaxf(red[4], red[5]), fmaxf(red[6], red[7]));

  const float L2E = 1.44269504f;
  const float range = qmx - qmn;
  const float hstep = range * (1.f / (G_ - 1));
  const int g   = tid & (G_ - 1);      // grid point 0..15
  const int seg = tid >> 4;            // j-segment 0..15 (32 terms each)
  const float gq = (qmn + hstep * (float)g) * L2E;
  float num = 0.f, den = 0.f;
  const float4* kv4 = (const float4*)&kvs[seg * 34];
#pragma unroll 4
  for (int j = 0; j < 16; ++j) {
    float4 pr = kv4[j];                // k,v,k,v (broadcast within 16-lane group)
    float e0 = __builtin_amdgcn_exp2f(gq * pr.x);
    den += e0; num = fmaf(e0, pr.y, num);
    float e1 = __builtin_amdgcn_exp2f(gq * pr.z);
    den += e1; num = fmaf(e1, pr.w, num);
  }
  part2[tid] = make_float2(num, den);
  __syncthreads();
  if (tid < G_) {
    float nsum = 0.f, dsum = 0.f;
#pragma unroll
    for (int s = 0; s < 16; ++s) {
      float2 pp = part2[tid + 16 * s];
      nsum += pp.x; dsum += pp.y;
    }
    fgrid[tid] = nsum / dsum;
  }
  __syncthreads();

  const float inv_h = (range > 1e-20f) ? (float)(G_ - 1) / range : 0.f;
#pragma unroll
  for (int ii = 0; ii < 2; ++ii) {
    const float q = ii ? q1 : q0;
    float u = (q - qmn) * inv_h;
    u = fminf(fmaxf(u, 0.f), (float)(G_ - 1));
    int gi = (int)u;
    gi = min(gi, G_ - 2);
    const float t = u - (float)gi;
    const float p0 = fgrid[max(gi - 1, 0)];
    const float p1 = fgrid[gi];
    const float p2 = fgrid[gi + 1];
    const float p3 = fgrid[min(gi + 2, G_ - 1)];
    // Catmull-Rom
    const float f = 0.5f * (2.f * p1 + t * ((p2 - p0)
                  + t * ((2.f * p0 - 5.f * p1 + 4.f * p2 - p3)
                  + t * (3.f * (p1 - p2) + p3 - p0))));
    const int i = ii * 256 + tid;
    out[(size_t)b * L_ + i] = fmaf(f, w0, b0) + (ii ? xres1 : xres0);
  }
}

extern "C" void kernel_launch(void* const* d_in, const int* in_sizes, int n_in,
                              void* d_out, int out_size, void* d_ws, size_t ws_size,
                              hipStream_t stream) {
  const float* x     = (const float*)d_in[0];
  const float* qkv_w = (const float*)d_in[1];
  const float* ipw   = (const float*)d_in[2];
  const float* ipb   = (const float*)d_in[3];
  const float* ow    = (const float*)d_in[4];
  const float* ob    = (const float*)d_in[5];
  float* out = (float*)d_out;

  float* co = (float*)d_ws;   // [1024][1536] fp32, 6 MB

  gemm_kernel<<<dim3(384), dim3(256), 0, stream>>>(x, qkv_w, co);

  attn_kernel<<<dim3(B_), dim3(256), 0, stream>>>(co, x, ipw, ipb, ow, ob, out);
}